// Round 5
// baseline (1030.551 us; speedup 1.0000x reference)
//
#include <hip/hip_runtime.h>
#include <hip/hip_fp16.h>

// LSTM B=256,T=512,IN=64,H=128,L=2 + FC:
//  K0 cvt    : x, w_ih0, w_ih1 -> fp16 (ws)
//  KG (MFMA) : xg0 = x16.Wih0^T + bias   [131072,512] fp16 (ws)
//  KR (L0)   : recurrent; writes h0_all fp16
//  KG (MFMA) : xg1 = h0_all.Wih1^T + bias
//  KR (L1)   : recurrent + fused FC -> out
// KR round-5 redesign: wave-local gates. lane = [gp(bit5) | u(bits1-4) | s(bit0)];
// wave w owns hidden units w*16..+15. Lane computes gate rows gp*128+wu and
// (gp+2)*128+wu for K-half s (64 weight VGPRs). K-halves combine via
// shfl_xor(1); gates exchange via shfl_xor(32) (replaces LDS+barrier);
// all 4 lanes/unit redundantly update c,h; h double-buffered in LDS ->
// ONE barrier/step. xg prefetched 2 steps ahead (covers ~900cyc HBM miss).

#define TT 512
#define MM (256 * 512)

typedef _Float16 f16x2 __attribute__((ext_vector_type(2)));
typedef _Float16 f16x8 __attribute__((ext_vector_type(8)));
typedef float f32x4 __attribute__((ext_vector_type(4)));

#define SH2(v, i) __builtin_shufflevector(v, v, 2*(i), 2*(i)+1)

__device__ __forceinline__ float fdot2_(f16x2 a, f16x2 b, float c) {
    return __builtin_amdgcn_fdot2(a, b, c, false);
}
__device__ __forceinline__ float sigmoid_f(float x) {
    float e = __expf(-x);
    return __builtin_amdgcn_rcpf(1.f + e);
}
__device__ __forceinline__ float tanh_f(float x) {
    float e = __expf(2.0f * x);
    return 1.0f - 2.0f * __builtin_amdgcn_rcpf(e + 1.0f);
}

// ---------------- K0: fp32 -> fp16 cvt (vector4) ----------------
__global__ void cvt_f32_f16(const float* __restrict__ src,
                            _Float16* __restrict__ dst, int n4) {
    int i = blockIdx.x * blockDim.x + threadIdx.x;
    int stride = gridDim.x * blockDim.x;
    for (; i < n4; i += stride) {
        float4 v = ((const float4*)src)[i];
        f16x2 a; a.x = (_Float16)v.x; a.y = (_Float16)v.y;
        f16x2 b; b.x = (_Float16)v.z; b.y = (_Float16)v.w;
        ((f16x2*)dst)[2 * i]     = a;
        ((f16x2*)dst)[2 * i + 1] = b;
    }
}

// ---------------- KG: xg[M,512] = A[M,K] . W[512,K]^T + (bih+bhh) ----------
__global__ __launch_bounds__(256, 1) void gemm_xg(
    const _Float16* __restrict__ A, const _Float16* __restrict__ W,
    const float* __restrict__ bih, const float* __restrict__ bhh,
    _Float16* __restrict__ out, int K)
{
    const int l  = threadIdx.x & 63;
    const int w  = threadIdx.x >> 6;
    const int mb = blockIdx.x * 64 + w * 16;
    const int c  = l & 15;
    const int q  = l >> 4;

    __shared__ float biasl[512];
    for (int i = threadIdx.x; i < 512; i += 256) biasl[i] = bih[i] + bhh[i];
    __syncthreads();

    f32x4 C[32];
    #pragma unroll
    for (int i = 0; i < 32; ++i) C[i] = (f32x4){0.f, 0.f, 0.f, 0.f};

    const int nks = K >> 5;
    for (int ks = 0; ks < nks; ++ks) {
        f16x8 Af = *(const f16x8*)(A + (size_t)(mb + c) * K + ks * 32 + q * 8);
        #pragma unroll
        for (int nt = 0; nt < 32; ++nt) {
            f16x8 Bf = *(const f16x8*)(W + (size_t)(nt * 16 + c) * K + ks * 32 + q * 8);
            C[nt] = __builtin_amdgcn_mfma_f32_16x16x32_f16(Af, Bf, C[nt], 0, 0, 0);
        }
    }
    #pragma unroll
    for (int nt = 0; nt < 32; ++nt) {
        float bv = biasl[nt * 16 + c];
        #pragma unroll
        for (int i = 0; i < 4; ++i) {
            int row = mb + q * 4 + i;
            out[(size_t)row * 512 + nt * 16 + c] = (_Float16)(C[nt][i] + bv);
        }
    }
}

// ---------------- KR: one recurrent layer (wave-local gates) ----------------
// flags bit0: write h_out (layer0); bit1: final-step FC -> out (layer1)
__global__ __launch_bounds__(512, 2) void lstm_rec(
    const float* __restrict__ whh,      // [512,128] fp32
    const _Float16* __restrict__ xg,    // [B*T,512] fp16 (bias included)
    _Float16* __restrict__ h_out,       // [B*T,128] fp16
    const float* __restrict__ fc_w, const float* __restrict__ fc_b,
    float* __restrict__ out, int flags)
{
    const int tid  = threadIdx.x;
    const int b    = blockIdx.x;
    const int lane = tid & 63;
    const int w    = tid >> 6;            // wave 0..7
    const int s    = lane & 1;            // K-half
    const int u    = (lane >> 1) & 15;    // unit in wave
    const int gp   = lane >> 5;           // gate pair: 0->{i,g}, 1->{f,o}
    const int wu   = w * 16 + u;          // hidden unit 0..127
    const int r1   = gp * 128 + wu;       // gate gp   (sigmoid)
    const int r2   = (gp + 2) * 128 + wu; // gate gp+2 (gp==0: tanh, else sigmoid)

    __shared__ __align__(16) _Float16 hbuf[2][128];
    __shared__ float h1f[128];

    // resident weights: rows r1, r2, K-half s => 64 VGPRs fp16
    f16x2 w1r[32], w2r[32];
    {
        const float4* p1 = (const float4*)(whh + r1 * 128 + s * 64);
        const float4* p2 = (const float4*)(whh + r2 * 128 + s * 64);
        #pragma unroll
        for (int k = 0; k < 16; ++k) {
            float4 v = p1[k];
            w1r[2 * k].x     = (_Float16)v.x; w1r[2 * k].y     = (_Float16)v.y;
            w1r[2 * k + 1].x = (_Float16)v.z; w1r[2 * k + 1].y = (_Float16)v.w;
            float4 t = p2[k];
            w2r[2 * k].x     = (_Float16)t.x; w2r[2 * k].y     = (_Float16)t.y;
            w2r[2 * k + 1].x = (_Float16)t.z; w2r[2 * k + 1].y = (_Float16)t.w;
        }
    }
    if (tid < 128) { hbuf[0][tid] = (_Float16)0.f; hbuf[1][tid] = (_Float16)0.f; }
    __syncthreads();

    float c = 0.f;
    const _Float16* xb = xg + (size_t)b * TT * 512;
    // 2-deep xg prefetch pipeline
    _Float16 x1c = xb[r1],       x2c = xb[r2];
    _Float16 x1n = xb[512 + r1], x2n = xb[512 + r2];

    #pragma unroll 1
    for (int step = 0; step < TT; ++step) {
        int pf = (step + 2 < TT) ? step + 2 : TT - 1;
        _Float16 x1p = xb[(size_t)pf * 512 + r1];
        _Float16 x2p = xb[(size_t)pf * 512 + r2];

        const f16x8* __restrict__ hv =
            (const f16x8*)(&hbuf[step & 1][0] + s * 64);
        float a0 = 0.f, a1 = 0.f, p0 = 0.f, p1 = 0.f;
        #pragma unroll
        for (int ch = 0; ch < 8; ++ch) {
            f16x8 h = hv[ch];
            a0 = fdot2_(SH2(h, 0), w1r[4 * ch + 0], a0);
            p0 = fdot2_(SH2(h, 0), w2r[4 * ch + 0], p0);
            a1 = fdot2_(SH2(h, 1), w1r[4 * ch + 1], a1);
            p1 = fdot2_(SH2(h, 1), w2r[4 * ch + 1], p1);
            a0 = fdot2_(SH2(h, 2), w1r[4 * ch + 2], a0);
            p0 = fdot2_(SH2(h, 2), w2r[4 * ch + 2], p0);
            a1 = fdot2_(SH2(h, 3), w1r[4 * ch + 3], a1);
            p1 = fdot2_(SH2(h, 3), w2r[4 * ch + 3], p1);
        }
        float d1 = a0 + a1, d2 = p0 + p1;
        d1 += __shfl_xor(d1, 1, 64);     // combine K-halves (both lanes get full)
        d2 += __shfl_xor(d2, 1, 64);
        float pre1 = d1 + (float)x1c;
        float pre2 = d2 + (float)x2c;
        float act1 = sigmoid_f(pre1);                       // i (gp=0) / f (gp=1)
        float zz   = (gp == 0) ? 2.f * pre2 : pre2;
        float sg2  = sigmoid_f(zz);
        float act2 = (gp == 0) ? 2.f * sg2 - 1.f : sg2;     // g (gp=0) / o (gp=1)
        float o1 = __shfl_xor(act1, 32, 64);                // partner gate pair
        float o2 = __shfl_xor(act2, 32, 64);
        float iv = (gp == 0) ? act1 : o1;
        float fv = (gp == 0) ? o1   : act1;
        float gv = (gp == 0) ? act2 : o2;
        float ov = (gp == 0) ? o2   : act2;
        c = fv * c + iv * gv;                // all 4 lanes/unit track same c
        float hh = ov * tanh_f(c);
        if ((lane & 33) == 0) {              // gp==0 && s==0: one lane per unit
            _Float16 h16 = (_Float16)hh;
            hbuf[(step + 1) & 1][wu] = h16;
            if (flags & 1)
                h_out[((size_t)b * TT + step) * 128 + wu] = h16;
            if ((flags & 2) && step == TT - 1) h1f[wu] = hh;
        }
        __syncthreads();                     // single barrier per step
        x1c = x1n; x2c = x2n; x1n = x1p; x2n = x2p;
    }

    if (flags & 2) {
        if (tid < 64) {
            float p = h1f[tid] * fc_w[tid] + h1f[tid + 64] * fc_w[tid + 64];
            #pragma unroll
            for (int off = 32; off > 0; off >>= 1) p += __shfl_down(p, off, 64);
            if (tid == 0) out[b] = p + fc_b[0];
        }
    }
}

extern "C" void kernel_launch(void* const* d_in, const int* in_sizes, int n_in,
                              void* d_out, int out_size, void* d_ws, size_t ws_size,
                              hipStream_t stream) {
    const float* x     = (const float*)d_in[0];
    const float* w_ih0 = (const float*)d_in[1];
    const float* w_hh0 = (const float*)d_in[2];
    const float* b_ih0 = (const float*)d_in[3];
    const float* b_hh0 = (const float*)d_in[4];
    const float* w_ih1 = (const float*)d_in[5];
    const float* w_hh1 = (const float*)d_in[6];
    const float* b_ih1 = (const float*)d_in[7];
    const float* b_hh1 = (const float*)d_in[8];
    const float* fc_w  = (const float*)d_in[9];
    const float* fc_b  = (const float*)d_in[10];
    float* out = (float*)d_out;

    // ws layout (bytes)
    char* ws = (char*)d_ws;
    _Float16* xg     = (_Float16*)(ws);                            // 134217728
    _Float16* h0_all = (_Float16*)(ws + 134217728);                //  33554432
    _Float16* x16    = (_Float16*)(ws + 134217728 + 33554432);     //  16777216
    _Float16* w0_16  = (_Float16*)(ws + 134217728 + 33554432 + 16777216);          // 65536
    _Float16* w1_16  = (_Float16*)(ws + 134217728 + 33554432 + 16777216 + 65536);  // 131072

    cvt_f32_f16<<<dim3(1024), dim3(256), 0, stream>>>(x, x16, (256 * 512 * 64) / 4);
    cvt_f32_f16<<<dim3(32), dim3(256), 0, stream>>>(w_ih0, w0_16, (512 * 64) / 4);
    cvt_f32_f16<<<dim3(64), dim3(256), 0, stream>>>(w_ih1, w1_16, (512 * 128) / 4);

    gemm_xg<<<dim3(MM / 64), dim3(256), 0, stream>>>(x16, w0_16, b_ih0, b_hh0, xg, 64);

    lstm_rec<<<dim3(256), dim3(512), 0, stream>>>(w_hh0, xg, h0_all,
                                                  fc_w, fc_b, out, 1);

    gemm_xg<<<dim3(MM / 64), dim3(256), 0, stream>>>(h0_all, w1_16, b_ih1, b_hh1, xg, 128);

    lstm_rec<<<dim3(256), dim3(512), 0, stream>>>(w_hh1, xg, h0_all,
                                                  fc_w, fc_b, out, 2);
}

// Round 7
// 1010.613 us; speedup vs baseline: 1.0197x; 1.0197x over previous
//
#include <hip/hip_runtime.h>
#include <hip/hip_fp16.h>

// LSTM B=256,T=512,IN=64,H=128,L=2 + FC:
//  K0 cvt    : x, w_ih0, w_ih1 -> fp16 (ws)
//  KG (MFMA) : xg0 = x16.Wih0^T + bias   [131072,512] fp16 (ws)
//  KR (L0)   : recurrent; writes h0_all fp16
//  KG (MFMA) : xg1 = h0_all.Wih1^T + bias
//  KR (L1)   : recurrent + fused FC -> out
// KR round-6: unit-per-quad. lane = [u(bits2-5)|q(bits0-1)]; the 4 lanes of a
// quad own hidden unit u; lane q holds ALL 4 gate rows of u over K-slice
// [q*32,q*32+32) = 64 weight VGPRs, 64 dot2/step. Gate totals via quad-local
// shfl_xor(1)+shfl_xor(2) (quad_perm DPP — NOT the ds_bpermute xor32 that
// regressed R5). xg seeded pre-reduction (1 fp16 load/thread/step). Every
// lane then updates c,h in-register: no gacts round-trip, ONE barrier/step,
// h double-buffered in LDS, 4 ds_read_b128/step.
// (R6 fix: hand-unrolled the j-loop — __builtin_shufflevector needs literal idx)

#define TT 512
#define MM (256 * 512)

typedef _Float16 f16x2 __attribute__((ext_vector_type(2)));
typedef _Float16 f16x8 __attribute__((ext_vector_type(8)));
typedef float f32x4 __attribute__((ext_vector_type(4)));

#define SH2(v, i) __builtin_shufflevector(v, v, 2*(i), 2*(i)+1)

__device__ __forceinline__ float fdot2_(f16x2 a, f16x2 b, float c) {
    return __builtin_amdgcn_fdot2(a, b, c, false);
}
__device__ __forceinline__ float sigmoid_f(float x) {
    float e = __expf(-x);
    return __builtin_amdgcn_rcpf(1.f + e);
}
__device__ __forceinline__ float tanh_f(float x) {
    float e = __expf(2.0f * x);
    return 1.0f - 2.0f * __builtin_amdgcn_rcpf(e + 1.0f);
}

// ---------------- K0: fp32 -> fp16 cvt (vector4) ----------------
__global__ void cvt_f32_f16(const float* __restrict__ src,
                            _Float16* __restrict__ dst, int n4) {
    int i = blockIdx.x * blockDim.x + threadIdx.x;
    int stride = gridDim.x * blockDim.x;
    for (; i < n4; i += stride) {
        float4 v = ((const float4*)src)[i];
        f16x2 a; a.x = (_Float16)v.x; a.y = (_Float16)v.y;
        f16x2 b; b.x = (_Float16)v.z; b.y = (_Float16)v.w;
        ((f16x2*)dst)[2 * i]     = a;
        ((f16x2*)dst)[2 * i + 1] = b;
    }
}

// ---------------- KG: xg[M,512] = A[M,K] . W[512,K]^T + (bih+bhh) ----------
__global__ __launch_bounds__(256, 1) void gemm_xg(
    const _Float16* __restrict__ A, const _Float16* __restrict__ W,
    const float* __restrict__ bih, const float* __restrict__ bhh,
    _Float16* __restrict__ out, int K)
{
    const int l  = threadIdx.x & 63;
    const int w  = threadIdx.x >> 6;
    const int mb = blockIdx.x * 64 + w * 16;
    const int c  = l & 15;
    const int q  = l >> 4;

    __shared__ float biasl[512];
    for (int i = threadIdx.x; i < 512; i += 256) biasl[i] = bih[i] + bhh[i];
    __syncthreads();

    f32x4 C[32];
    #pragma unroll
    for (int i = 0; i < 32; ++i) C[i] = (f32x4){0.f, 0.f, 0.f, 0.f};

    const int nks = K >> 5;
    for (int ks = 0; ks < nks; ++ks) {
        f16x8 Af = *(const f16x8*)(A + (size_t)(mb + c) * K + ks * 32 + q * 8);
        #pragma unroll
        for (int nt = 0; nt < 32; ++nt) {
            f16x8 Bf = *(const f16x8*)(W + (size_t)(nt * 16 + c) * K + ks * 32 + q * 8);
            C[nt] = __builtin_amdgcn_mfma_f32_16x16x32_f16(Af, Bf, C[nt], 0, 0, 0);
        }
    }
    #pragma unroll
    for (int nt = 0; nt < 32; ++nt) {
        float bv = biasl[nt * 16 + c];
        #pragma unroll
        for (int i = 0; i < 4; ++i) {
            int row = mb + q * 4 + i;
            out[(size_t)row * 512 + nt * 16 + c] = (_Float16)(C[nt][i] + bv);
        }
    }
}

// ---------------- KR: one recurrent layer (unit-per-quad) ----------------
// flags bit0: write h_out (layer0); bit1: final-step FC -> out (layer1)
__global__ __launch_bounds__(512, 2) void lstm_rec(
    const float* __restrict__ whh,      // [512,128] fp32
    const _Float16* __restrict__ xg,    // [B*T,512] fp16 (bias included)
    _Float16* __restrict__ h_out,       // [B*T,128] fp16
    const float* __restrict__ fc_w, const float* __restrict__ fc_b,
    float* __restrict__ out, int flags)
{
    const int tid = threadIdx.x;
    const int b   = blockIdx.x;
    const int q   = tid & 3;                        // K-quarter
    const int u   = (tid >> 6) * 16 + ((tid & 63) >> 2);  // hidden unit 0..127

    __shared__ __align__(16) _Float16 hbuf[2][128];
    __shared__ float h1f[128];

    // resident weights: all 4 gate rows of unit u, K-slice [q*32, q*32+32)
    // = 4 x 16 f16x2 = 64 VGPRs
    f16x2 wr[4][16];
    #pragma unroll
    for (int g = 0; g < 4; ++g) {
        const float4* p = (const float4*)(whh + (g * 128 + u) * 128 + q * 32);
        #pragma unroll
        for (int k = 0; k < 8; ++k) {
            float4 v = p[k];
            wr[g][2 * k].x     = (_Float16)v.x; wr[g][2 * k].y     = (_Float16)v.y;
            wr[g][2 * k + 1].x = (_Float16)v.z; wr[g][2 * k + 1].y = (_Float16)v.w;
        }
    }
    if (tid < 128) {
        hbuf[0][tid] = (_Float16)0.f;
        hbuf[1][tid] = (_Float16)0.f;
    }
    __syncthreads();

    float c = 0.f;
    // lane's xg element: gate q, unit u
    const _Float16* xp = xg + (size_t)b * TT * 512 + q * 128 + u;
    float x0 = (float)xp[0];
    float x1 = (float)xp[512];

    #pragma unroll 1
    for (int step = 0; step < TT; ++step) {
        int pf = (step + 2 < TT) ? step + 2 : TT - 1;
        float x2 = (float)xp[(size_t)pf * 512];

        const f16x8* __restrict__ hv =
            (const f16x8*)(&hbuf[step & 1][0] + q * 32);

        // seed acc[g] with xg for gate g on lane q==g (counted once post-reduce)
        float acc0 = (q == 0) ? x0 : 0.f;
        float acc1 = (q == 1) ? x0 : 0.f;
        float acc2 = (q == 2) ? x0 : 0.f;
        float acc3 = (q == 3) ? x0 : 0.f;

        #pragma unroll
        for (int ch = 0; ch < 4; ++ch) {
            f16x8 h = hv[ch];
            f16x2 hp0 = SH2(h, 0);
            f16x2 hp1 = SH2(h, 1);
            f16x2 hp2 = SH2(h, 2);
            f16x2 hp3 = SH2(h, 3);
            int k = ch * 4;
            acc0 = fdot2_(hp0, wr[0][k + 0], acc0);
            acc1 = fdot2_(hp0, wr[1][k + 0], acc1);
            acc2 = fdot2_(hp0, wr[2][k + 0], acc2);
            acc3 = fdot2_(hp0, wr[3][k + 0], acc3);
            acc0 = fdot2_(hp1, wr[0][k + 1], acc0);
            acc1 = fdot2_(hp1, wr[1][k + 1], acc1);
            acc2 = fdot2_(hp1, wr[2][k + 1], acc2);
            acc3 = fdot2_(hp1, wr[3][k + 1], acc3);
            acc0 = fdot2_(hp2, wr[0][k + 2], acc0);
            acc1 = fdot2_(hp2, wr[1][k + 2], acc1);
            acc2 = fdot2_(hp2, wr[2][k + 2], acc2);
            acc3 = fdot2_(hp2, wr[3][k + 2], acc3);
            acc0 = fdot2_(hp3, wr[0][k + 3], acc0);
            acc1 = fdot2_(hp3, wr[1][k + 3], acc1);
            acc2 = fdot2_(hp3, wr[2][k + 3], acc2);
            acc3 = fdot2_(hp3, wr[3][k + 3], acc3);
        }
        // quad-local reduction (quad_perm DPP): full K sum on every lane
        acc0 += __shfl_xor(acc0, 1, 64); acc0 += __shfl_xor(acc0, 2, 64);
        acc1 += __shfl_xor(acc1, 1, 64); acc1 += __shfl_xor(acc1, 2, 64);
        acc2 += __shfl_xor(acc2, 1, 64); acc2 += __shfl_xor(acc2, 2, 64);
        acc3 += __shfl_xor(acc3, 1, 64); acc3 += __shfl_xor(acc3, 2, 64);

        float iv = sigmoid_f(acc0);
        float fv = sigmoid_f(acc1);
        float gv = tanh_f(acc2);
        float ov = sigmoid_f(acc3);
        c = fv * c + iv * gv;
        float hh = ov * tanh_f(c);

        if (q == 0) {
            _Float16 h16 = (_Float16)hh;
            hbuf[(step + 1) & 1][u] = h16;
            if (flags & 1)
                h_out[((size_t)b * TT + step) * 128 + u] = h16;
            if ((flags & 2) && step == TT - 1) h1f[u] = hh;
        }
        __syncthreads();   // single barrier per step
        x0 = x1; x1 = x2;
    }

    if (flags & 2) {
        if (tid < 64) {
            float p = h1f[tid] * fc_w[tid] + h1f[tid + 64] * fc_w[tid + 64];
            #pragma unroll
            for (int off = 32; off > 0; off >>= 1) p += __shfl_down(p, off, 64);
            if (tid == 0) out[b] = p + fc_b[0];
        }
    }
}

extern "C" void kernel_launch(void* const* d_in, const int* in_sizes, int n_in,
                              void* d_out, int out_size, void* d_ws, size_t ws_size,
                              hipStream_t stream) {
    const float* x     = (const float*)d_in[0];
    const float* w_ih0 = (const float*)d_in[1];
    const float* w_hh0 = (const float*)d_in[2];
    const float* b_ih0 = (const float*)d_in[3];
    const float* b_hh0 = (const float*)d_in[4];
    const float* w_ih1 = (const float*)d_in[5];
    const float* w_hh1 = (const float*)d_in[6];
    const float* b_ih1 = (const float*)d_in[7];
    const float* b_hh1 = (const float*)d_in[8];
    const float* fc_w  = (const float*)d_in[9];
    const float* fc_b  = (const float*)d_in[10];
    float* out = (float*)d_out;

    // ws layout (bytes)
    char* ws = (char*)d_ws;
    _Float16* xg     = (_Float16*)(ws);                            // 134217728
    _Float16* h0_all = (_Float16*)(ws + 134217728);                //  33554432
    _Float16* x16    = (_Float16*)(ws + 134217728 + 33554432);     //  16777216
    _Float16* w0_16  = (_Float16*)(ws + 134217728 + 33554432 + 16777216);          // 65536
    _Float16* w1_16  = (_Float16*)(ws + 134217728 + 33554432 + 16777216 + 65536);  // 131072

    cvt_f32_f16<<<dim3(1024), dim3(256), 0, stream>>>(x, x16, (256 * 512 * 64) / 4);
    cvt_f32_f16<<<dim3(32), dim3(256), 0, stream>>>(w_ih0, w0_16, (512 * 64) / 4);
    cvt_f32_f16<<<dim3(64), dim3(256), 0, stream>>>(w_ih1, w1_16, (512 * 128) / 4);

    gemm_xg<<<dim3(MM / 64), dim3(256), 0, stream>>>(x16, w0_16, b_ih0, b_hh0, xg, 64);

    lstm_rec<<<dim3(256), dim3(512), 0, stream>>>(w_hh0, xg, h0_all,
                                                  fc_w, fc_b, out, 1);

    gemm_xg<<<dim3(MM / 64), dim3(256), 0, stream>>>(h0_all, w1_16, b_ih1, b_hh1, xg, 128);

    lstm_rec<<<dim3(256), dim3(512), 0, stream>>>(w_hh1, xg, h0_all,
                                                  fc_w, fc_b, out, 2);
}